// Round 4
// baseline (1189.558 us; speedup 1.0000x reference)
//
#include <hip/hip_runtime.h>

// TitansMemory: per-row delta-rule-with-momentum scan. B=16, L=8192, DK=DV=128.
//   s = C_S*(w·k - v) ; m̂ = β m̂ + s k ; w = (1-α) w + m̂ ; y = w·q
// Mapping: TWO rows per wave (lanes 0-31 row0, 32-63 row1), 4 cols/lane (f4).
// 1024 single-wave blocks = 1 wave/SIMD; pinned asm global loads with counted
// s_waitcnt vmcnt(24) (two 8-step chunks in flight) — harness-verified r3.
// Round 4 change: DEFERRED-BATCHED y-reduction. Evidence: 304 cyc/step vs ~64
// issue-cycles; cross-lane ops cost ~25-45 cyc each (r1/r3 fit). The y
// reduction (5 dependent cross-lane/step) is off the recurrence chain ->
// defer: per step keep only a per-lane fold ey[j]; at chunk end batch-reduce
// 8 values with dual-input permlane16_swap pairing (swap(a,b): a'+b' =
// xor16-pairwise sums of BOTH values in alternating 16-rows) + 4 fused DPP
// row_ror adds -> 24 independent cross-lane ops per 8 steps (3/step,
// latency-hidden) instead of 5/step dependent. Store: 4 predicated lanes
// (lane&15==0) per pair-reg, issued BEFORE ISSUE_CHUNK to keep vmcnt(24)
// draining only old loads+own stores.

#define L_ 8192
#define D_ 128

typedef __attribute__((ext_vector_type(4))) float f4;
typedef __attribute__((ext_vector_type(2))) float f2;
typedef __attribute__((ext_vector_type(2))) unsigned int u2;

constexpr float A_    = 0.98f;
constexpr float BETA_ = 0.9f;
constexpr float C_S   = -0.02f;  // -2*lr*(1-beta)

template <int CTRL>
__device__ __forceinline__ float dpp_add(float x) {
  int y = __builtin_amdgcn_update_dpp(0, __float_as_int(x), CTRL, 0xF, 0xF, true);
  return x + __int_as_float(y);
}

// Half-wave (32-lane) all-reduce: lanes 0-31 -> sum over lanes 0-31,
// lanes 32-63 -> sum over lanes 32-63. Pure VALU. (Harness-verified r2/r3.)
__device__ __forceinline__ float half_sum_all(float x) {
  x = dpp_add<0x121>(x);  // row_ror:1
  x = dpp_add<0x122>(x);  // row_ror:2
  x = dpp_add<0x124>(x);  // row_ror:4
  x = dpp_add<0x128>(x);  // row_ror:8
  u2 p = __builtin_amdgcn_permlane16_swap(__float_as_uint(x), __float_as_uint(x),
                                          false, false);
  return __uint_as_float(p.x) + __uint_as_float(p.y);
}

// Pinned loads: asm volatile keeps issue placement and register residency.
#define GLD4(dst, addr, OFF) \
  asm volatile("global_load_dwordx4 %0, %1, off offset:" OFF : "=v"(dst) : "v"(addr))
#define GLD1(dst, addr, OFF) \
  asm volatile("global_load_dword %0, %1, off offset:" OFF : "=v"(dst) : "v"(addr))

#define ISSUE_CHUNK(kb, qb, vb)                            \
  do {                                                     \
    GLD4(kb[0], ka64, "0");    GLD4(qb[0], qa64, "0");    GLD1(vb[0], va64, "0");    \
    GLD4(kb[1], ka64, "512");  GLD4(qb[1], qa64, "512");  GLD1(vb[1], va64, "512");  \
    GLD4(kb[2], ka64, "1024"); GLD4(qb[2], qa64, "1024"); GLD1(vb[2], va64, "1024"); \
    GLD4(kb[3], ka64, "1536"); GLD4(qb[3], qa64, "1536"); GLD1(vb[3], va64, "1536"); \
    GLD4(kb[4], ka64, "2048"); GLD4(qb[4], qa64, "2048"); GLD1(vb[4], va64, "2048"); \
    GLD4(kb[5], ka64, "2560"); GLD4(qb[5], qa64, "2560"); GLD1(vb[5], va64, "2560"); \
    GLD4(kb[6], ka64, "3072"); GLD4(qb[6], qa64, "3072"); GLD1(vb[6], va64, "3072"); \
    GLD4(kb[7], ka64, "3584"); GLD4(qb[7], qa64, "3584"); GLD1(vb[7], va64, "3584"); \
    uint64_t bump_ = (sc < 1023) ? 4096u : 0u;             \
    ka64 += bump_; qa64 += bump_; va64 += bump_; ++sc;     \
  } while (0)

#define WAITP                                              \
  do {                                                     \
    asm volatile("s_waitcnt vmcnt(24)");                   \
    __builtin_amdgcn_sched_barrier(0);                     \
  } while (0)

__global__ __launch_bounds__(64, 1)
void TitansMemory_188978561365_kernel(const float* __restrict__ Q,
                                      const float* __restrict__ K,
                                      const float* __restrict__ V,
                                      float* __restrict__ Y) {
  const int lane  = threadIdx.x;              // 0..63
  const int wid   = blockIdx.x;               // 0..1023
  const int batch = wid >> 6;                 // 64 waves per batch (128 rows)
  const int col   = (lane & 31) << 2;         // 4 k-cols per lane

  const size_t bbase = (size_t)batch * (size_t)L_ * D_;
  uint64_t ka64 = (uint64_t)(K + bbase + col);
  uint64_t qa64 = (uint64_t)(Q + bbase + col);
  uint64_t va64 = (uint64_t)(V + bbase + ((wid & 63) << 1) + (lane >> 5));
  // Store base: group g=lane>>4 of each pair-reg holds (row = g>>1,
  // t_parity = g&1); lanes 0,16,32,48 store.
  float* yb = Y + bbase + ((wid & 63) << 1) + (lane >> 5)
                + (size_t)((lane >> 4) & 1) * D_;
  int sc = 0;  // chunks issued (tail clamp)

  const f4 av = {A_, A_, A_, A_};
  const f4 bv = {BETA_, BETA_, BETA_, BETA_};

  f4 w = {0.f, 0.f, 0.f, 0.f}, m = {0.f, 0.f, 0.f, 0.f};

  f4 kA[8], qA[8]; float vA[8];
  f4 kB[8], qB[8]; float vB[8];
  float ey[8];

  auto step = [&](const f4& k, const f4& q, float v) -> float {
    // ---- dot = w·k  (serial chain) ----
    f4 d = w * k;
    f2 dp = {d.x + d.z, d.y + d.w};        // v_pk_add_f32
    float dot = half_sum_all(dp.x + dp.y);
    float s = fmaf(C_S, dot, (-C_S) * v);
    f4 s4 = {s, s, s, s};
    // ---- m̂ = β m̂ + s k ; w = A w + m̂ ----
    m = __builtin_elementwise_fma(s4, k, bv * m);
    w = __builtin_elementwise_fma(av, w, m);
    // ---- y partial only (reduction deferred) ----
    f4 e = w * q;
    f2 ep = {e.x + e.z, e.y + e.w};
    return ep.x + ep.y;
  };

  // Batch-reduce 8 y-partials (both rows at once) + predicated store.
  auto flushY = [&]() {
#pragma unroll
    for (int p = 0; p < 4; ++p) {
      u2 r = __builtin_amdgcn_permlane16_swap(__float_as_uint(ey[2 * p]),
                                              __float_as_uint(ey[2 * p + 1]),
                                              false, false);
      float c = __uint_as_float(r.x) + __uint_as_float(r.y);
      c = dpp_add<0x121>(c);
      c = dpp_add<0x122>(c);
      c = dpp_add<0x124>(c);
      c = dpp_add<0x128>(c);
      // 16-group g: g0: row0 t=2p | g1: row0 t=2p+1 | g2: row1 t=2p | g3: row1 t=2p+1
      if ((lane & 15) == 0) yb[(size_t)(2 * p) * D_] = c;
    }
    yb += 8 * D_;
  };

  // Prologue: two chunks in flight (48 loads).
  ISSUE_CHUNK(kA, qA, vA);
  ISSUE_CHUNK(kB, qB, vB);

  for (int it = 0; it < L_ / 32; ++it) {   // 256 windows of 32 steps
    WAITP;
#pragma unroll
    for (int j = 0; j < 8; ++j) ey[j] = step(kA[j], qA[j], vA[j]);
    flushY();
    ISSUE_CHUNK(kA, qA, vA);
    WAITP;
#pragma unroll
    for (int j = 0; j < 8; ++j) ey[j] = step(kB[j], qB[j], vB[j]);
    flushY();
    ISSUE_CHUNK(kB, qB, vB);
    WAITP;
#pragma unroll
    for (int j = 0; j < 8; ++j) ey[j] = step(kA[j], qA[j], vA[j]);
    flushY();
    ISSUE_CHUNK(kA, qA, vA);
    WAITP;
#pragma unroll
    for (int j = 0; j < 8; ++j) ey[j] = step(kB[j], qB[j], vB[j]);
    flushY();
    ISSUE_CHUNK(kB, qB, vB);
  }
}

extern "C" void kernel_launch(void* const* d_in, const int* in_sizes, int n_in,
                              void* d_out, int out_size, void* d_ws, size_t ws_size,
                              hipStream_t stream) {
  const float* Q = (const float*)d_in[0];
  const float* K = (const float*)d_in[1];
  const float* V = (const float*)d_in[2];
  float* Y = (float*)d_out;
  dim3 grid(1024), block(64);
  hipLaunchKernelGGL(TitansMemory_188978561365_kernel, grid, block, 0, stream,
                     Q, K, V, Y);
}